// Round 2
// baseline (138.876 us; speedup 1.0000x reference)
//
#include <hip/hip_runtime.h>
#include <math.h>

// FocalLoss (RetinaNet-style) for B=16, A=200000, C=2, M=8, f32.
// Inputs (setup_inputs order):
//   d_in[0] classifications (B,A,C) f32
//   d_in[1] regressions     (B,A,4) f32
//   d_in[2] anchors         (1,A,4) f32
//   d_in[3] annotations     (B,M,5) f32
// Output: d_out = [cls_loss_mean, reg_loss_mean] (2 f32)
//
// Key semantic notes (verified against the JAX reference):
//  * invalid annotations (label==-1) are staged as zero-area boxes -> IoU 0,
//    which matches the reference's iou=-1 masking for every observable
//    (pos/care thresholds and argmax-when-pos), including the empty-image
//    path: all-IoU-0 => pos=false, care=true => the t=0 focal term, which is
//    exactly cls_empty; num_pos=0 => finalize divides cls by 1, zeroes reg.
//  * pos  <=> iou_max >= 0.5  <=> 2*bi >= bu      (exact; x0.5 is exact)
//  * care <=> pos || iou_max < 0.4 <=> pos || bi < 0.4f*bu
//  * running argmax kept as a cross-multiplied fraction (bi/bu) -> exact
//    real-number ordering, strict '>' keeps the first max like jnp.argmax.

namespace {

constexpr int B = 16;
constexpr int A = 200000;
constexpr int M = 8;
constexpr float F_ALPHA = 0.25f;   // ALPHA
constexpr int   TIP_L    = 0;
constexpr int   CARINA_L = 1;

__device__ __forceinline__ float rfl(float x) {
    // wave-uniform value -> SGPR, so inner-loop VALU ops fold it as the
    // (single allowed) scalar operand instead of burning VGPRs/LDS reads.
    return __uint_as_float(__builtin_amdgcn_readfirstlane(__float_as_uint(x)));
}

__device__ __forceinline__ float smooth_l1(float x) {
    float d = fabsf(x);
    return (d <= (1.0f / 9.0f)) ? (4.5f * d) * d : d - (0.5f / 9.0f);
}

__global__ __launch_bounds__(256)
void focal_main(const float* __restrict__ cls,
                const float* __restrict__ reg,
                const float* __restrict__ anc,
                const float* __restrict__ ann,
                double* __restrict__ ws)
{
    const int b   = blockIdx.y;
    const int tid = threadIdx.x;

    __shared__ float sb[M][5];   // sanitized x1,y1,x2,y2,area (IoU loop)
    __shared__ float sg[M][5];   // raw gcx,gcy,gw(clamped),gh(clamped),weight
    __shared__ int   slab[M];

    if (tid < M) {
        const float* a5 = ann + (b * M + tid) * 5;
        const float x1 = a5[0], y1 = a5[1], x2 = a5[2], y2 = a5[3], lb = a5[4];
        const bool v = (lb != -1.0f);
        const float zx1 = v ? x1 : 0.0f, zy1 = v ? y1 : 0.0f;
        const float zx2 = v ? x2 : 0.0f, zy2 = v ? y2 : 0.0f;
        sb[tid][0] = zx1; sb[tid][1] = zy1; sb[tid][2] = zx2; sb[tid][3] = zy2;
        sb[tid][4] = (zx2 - zx1) * (zy2 - zy1);
        const float gw = x2 - x1, gh = y2 - y1;
        sg[tid][0] = x1 + 0.5f * gw;
        sg[tid][1] = y1 + 0.5f * gh;
        sg[tid][2] = fmaxf(gw, 1.0f);
        sg[tid][3] = fmaxf(gh, 1.0f);
        const int l = (int)lb;
        sg[tid][4] = (l == TIP_L) ? 1.2f : (l == CARINA_L) ? 0.8f : 1.0f;
        slab[tid]  = l;
    }
    __syncthreads();

    // hoist annotation boxes into SGPRs
    float bx1[M], by1[M], bx2[M], by2[M], bar[M];
#pragma unroll
    for (int j = 0; j < M; ++j) {
        bx1[j] = rfl(sb[j][0]); by1[j] = rfl(sb[j][1]);
        bx2[j] = rfl(sb[j][2]); by2[j] = rfl(sb[j][3]);
        bar[j] = rfl(sb[j][4]);
    }

    const float* clsb = cls + (size_t)b * A * 2;
    const float* regb = reg + (size_t)b * A * 4;

    float cls_acc = 0.0f, reg_acc = 0.0f, np_acc = 0.0f;

    const int stride = gridDim.x * blockDim.x;
    for (int a = blockIdx.x * blockDim.x + tid; a < A; a += stride) {
        const float4 ab = reinterpret_cast<const float4*>(anc)[a];
        const float aw = ab.z - ab.x;
        const float ah = ab.w - ab.y;
        const float area_a = aw * ah;

        // running IoU max as fraction bi/bu (bu > 0 always)
        float bi = -1.0f, bu = 1.0f;
        int   arg = 0;
#pragma unroll
        for (int j = 0; j < M; ++j) {
            float iw = fminf(ab.z, bx2[j]) - fmaxf(ab.x, bx1[j]);
            float ih = fminf(ab.w, by2[j]) - fmaxf(ab.y, by1[j]);
            iw = fmaxf(iw, 0.0f);
            ih = fmaxf(ih, 0.0f);
            const float inter = iw * ih;
            const float ua = fmaxf(area_a + bar[j] - inter, 1e-8f);
            // iou_j > iou_best  <=>  inter*bu > bi*ua
            if (inter * bu > bi * ua) { bi = inter; bu = ua; arg = j; }
        }

        const bool pos  = (2.0f * bi >= bu);          // iou_max >= 0.5
        const bool care = pos || (bi < 0.4f * bu);    // pos || iou_max < 0.4

        const float2 pc = *reinterpret_cast<const float2*>(clsb + 2 * (size_t)a);
        const float p0 = fminf(fmaxf(pc.x, 1e-4f), 0.9999f);
        const float p1 = fminf(fmaxf(pc.y, 1e-4f), 0.9999f);
        const float n0 = (1.0f - F_ALPHA) * (p0 * p0) * (-__logf(1.0f - p0));
        const float n1 = (1.0f - F_ALPHA) * (p1 * p1) * (-__logf(1.0f - p1));
        float term = n0 + n1;

        if (pos) {
            // rare path (~0.5% of anchors; ~27% of waves hit it)
            np_acc += 1.0f;
            const int lab = slab[arg];
            const float pl = (lab == 0) ? p0 : p1;
            const float posterm =
                F_ALPHA * ((1.0f - pl) * (1.0f - pl)) * (-__logf(pl));
            term = posterm + ((lab == 0) ? n1 : n0);

            const float4 rg =
                *reinterpret_cast<const float4*>(regb + 4 * (size_t)a);
            const float acx = ab.x + 0.5f * aw;
            const float acy = ab.y + 0.5f * ah;
            const float t0r = ((sg[arg][0] - acx) / aw) / 0.1f;
            const float t1r = ((sg[arg][1] - acy) / ah) / 0.1f;
            const float t2r = logf(sg[arg][2] / aw) / 0.2f;
            const float t3r = logf(sg[arg][3] / ah) / 0.2f;
            const float rl = smooth_l1(t0r - rg.x) + smooth_l1(t1r - rg.y)
                           + smooth_l1(t2r - rg.z) + smooth_l1(t3r - rg.w);
            reg_acc += rl * sg[arg][4];
        }
        if (care) cls_acc += term;
    }

    // block reduction: wave shuffle, then LDS across 4 waves
#pragma unroll
    for (int off = 32; off > 0; off >>= 1) {
        cls_acc += __shfl_down(cls_acc, off);
        reg_acc += __shfl_down(reg_acc, off);
        np_acc  += __shfl_down(np_acc,  off);
    }
    __shared__ double rbuf[4][3];
    const int wid = tid >> 6;
    if ((tid & 63) == 0) {
        rbuf[wid][0] = (double)cls_acc;
        rbuf[wid][1] = (double)reg_acc;
        rbuf[wid][2] = (double)np_acc;
    }
    __syncthreads();
    if (tid == 0) {
        double c = 0.0, r = 0.0, n = 0.0;
#pragma unroll
        for (int w = 0; w < 4; ++w) {
            c += rbuf[w][0]; r += rbuf[w][1]; n += rbuf[w][2];
        }
        atomicAdd(&ws[b * 3 + 0], c);
        atomicAdd(&ws[b * 3 + 1], r);
        atomicAdd(&ws[b * 3 + 2], n);
    }
}

__global__ __launch_bounds__(64)
void focal_final(const double* __restrict__ ws, float* __restrict__ out)
{
    const int lane = threadIdx.x;
    float cl = 0.0f, rl = 0.0f;
    if (lane < B) {
        const float c   = (float)ws[lane * 3 + 0];
        const float r   = (float)ws[lane * 3 + 1];
        const float npf = (float)ws[lane * 3 + 2];
        cl = c / fmaxf(npf, 1.0f);
        rl = (npf > 0.0f) ? r / fmaxf(npf * 4.0f, 1.0f) : 0.0f;
    }
#pragma unroll
    for (int off = 32; off > 0; off >>= 1) {
        cl += __shfl_down(cl, off);
        rl += __shfl_down(rl, off);
    }
    if (lane == 0) {
        out[0] = cl * (1.0f / 16.0f);
        out[1] = rl * (1.0f / 16.0f);
    }
}

} // namespace

extern "C" void kernel_launch(void* const* d_in, const int* in_sizes, int n_in,
                              void* d_out, int out_size, void* d_ws, size_t ws_size,
                              hipStream_t stream)
{
    const float* cls = (const float*)d_in[0];
    const float* reg = (const float*)d_in[1];
    const float* anc = (const float*)d_in[2];
    const float* ann = (const float*)d_in[3];
    float*  out = (float*)d_out;
    double* ws  = (double*)d_ws;

    // d_ws is re-poisoned to 0xAA before every launch — zero the accumulators.
    hipMemsetAsync(ws, 0, B * 3 * sizeof(double), stream);

    dim3 grid(128, B);
    focal_main<<<grid, dim3(256), 0, stream>>>(cls, reg, anc, ann, ws);
    focal_final<<<1, dim3(64), 0, stream>>>(ws, out);
}

// Round 4
// 116.785 us; speedup vs baseline: 1.1892x; 1.1892x over previous
//
#include <hip/hip_runtime.h>
#include <math.h>

// FocalLoss (RetinaNet-style) for B=16, A=200000, C=2, M=8, f32.
// Inputs (setup_inputs order):
//   d_in[0] classifications (B,A,C) f32
//   d_in[1] regressions     (B,A,4) f32
//   d_in[2] anchors         (1,A,4) f32
//   d_in[3] annotations     (B,M,5) f32
// Output: d_out = [cls_loss_mean, reg_loss_mean] (2 f32)
//
// Semantics notes (same as the round-2 kernel that passed, absmax 0.0):
//  * invalid annotations staged as zero-area boxes -> IoU 0; matches the
//    reference's -1 masking for every observable, including the empty-image
//    path (all IoU 0 => pos=false, care=true => the t=0 focal term == cls_empty,
//    num_pos=0 => finalize divides by 1, zeroes reg).
//  * pos  <=> 2*bi >= bu ; care <=> pos || bi < 0.4f*bu  (IoU kept as an
//    exact cross-multiplied fraction -- instruction-identical to round 2 so
//    the pos/care classification cannot flip).
// Round-3 changes (latency-bound fix, counters: VALUBusy 42%, HBM 4%):
//  * 3x pairwise-unrolled main loop (6 unconditional iters + guarded tail):
//    paired loads + two independent compute chains per pair for ILP.
//  * pos path: __fdividef + log2-difference (no v_div sequences).
//  * per-block ws slots instead of global atomics; memset node dropped.
//  * grid (x=image, y=chunk): consecutive blocks share the anchor chunk in L2.
// (Round 4 = round 3 resubmitted verbatim: GPU was unavailable, kernel never ran.)

namespace {

constexpr int B = 16;
constexpr int A = 200000;
constexpr int M = 8;
constexpr int CHUNKS = 128;            // blocks per image
constexpr int S = CHUNKS * 256;        // anchor stride = 32768
constexpr int TAIL = A - 6 * S;        // 3392
constexpr float LN2 = 0.6931471805599453f;
constexpr float NEG_K = 0.75f * LN2;   // (1-ALPHA) * ln2
constexpr float POS_K = 0.25f * LN2;   // ALPHA * ln2

__device__ __forceinline__ float rfl(float x) {
    // wave-uniform value -> SGPR; inner-loop VALU ops fold it as the scalar
    // operand instead of burning VGPRs/LDS reads.
    return __uint_as_float(__builtin_amdgcn_readfirstlane(__float_as_uint(x)));
}

__device__ __forceinline__ float smooth_l1(float x) {
    float d = fabsf(x);
    return (d <= (1.0f / 9.0f)) ? (4.5f * d) * d : d - (0.5f / 9.0f);
}

__global__ __launch_bounds__(256)
void focal_main(const float* __restrict__ cls,
                const float* __restrict__ reg,
                const float* __restrict__ anc,
                const float* __restrict__ ann,
                float* __restrict__ ws)
{
    const int b   = blockIdx.x;    // image
    const int blk = blockIdx.y;    // anchor chunk
    const int tid = threadIdx.x;

    __shared__ float sb[M][5];   // sanitized x1,y1,x2,y2,area (IoU loop)
    __shared__ float sg[M][5];   // gcx,gcy,gw(clamped),gh(clamped),weight
    __shared__ int   slab[M];

    if (tid < M) {
        const float* a5 = ann + (b * M + tid) * 5;
        const float x1 = a5[0], y1 = a5[1], x2 = a5[2], y2 = a5[3], lb = a5[4];
        const bool v = (lb != -1.0f);
        const float zx1 = v ? x1 : 0.0f, zy1 = v ? y1 : 0.0f;
        const float zx2 = v ? x2 : 0.0f, zy2 = v ? y2 : 0.0f;
        sb[tid][0] = zx1; sb[tid][1] = zy1; sb[tid][2] = zx2; sb[tid][3] = zy2;
        sb[tid][4] = (zx2 - zx1) * (zy2 - zy1);
        const float gw = x2 - x1, gh = y2 - y1;
        sg[tid][0] = x1 + 0.5f * gw;
        sg[tid][1] = y1 + 0.5f * gh;
        sg[tid][2] = fmaxf(gw, 1.0f);
        sg[tid][3] = fmaxf(gh, 1.0f);
        const int l = (int)lb;
        sg[tid][4] = (l == 0) ? 1.2f : (l == 1) ? 0.8f : 1.0f;
        slab[tid]  = l;
    }
    __syncthreads();

    // hoist annotation boxes into SGPRs
    float bx1[M], by1[M], bx2[M], by2[M], bar[M];
#pragma unroll
    for (int j = 0; j < M; ++j) {
        bx1[j] = rfl(sb[j][0]); by1[j] = rfl(sb[j][1]);
        bx2[j] = rfl(sb[j][2]); by2[j] = rfl(sb[j][3]);
        bar[j] = rfl(sb[j][4]);
    }

    const float* clsb = cls + (size_t)b * A * 2;
    const float* regb = reg + (size_t)b * A * 4;

    float cls_acc = 0.0f, reg_acc = 0.0f, np_acc = 0.0f;

    auto body = [&](const float4 ab, const float2 pc, const int a) {
        const float aw = ab.z - ab.x;
        const float ah = ab.w - ab.y;
        const float area_a = aw * ah;

        // running IoU max as fraction bi/bu (bu > 0 always) -- KEEP the op
        // sequence identical to the round-2 kernel (classification parity).
        float bi = -1.0f, bu = 1.0f;
        int   arg = 0;
#pragma unroll
        for (int j = 0; j < M; ++j) {
            float iw = fminf(ab.z, bx2[j]) - fmaxf(ab.x, bx1[j]);
            float ih = fminf(ab.w, by2[j]) - fmaxf(ab.y, by1[j]);
            iw = fmaxf(iw, 0.0f);
            ih = fmaxf(ih, 0.0f);
            const float inter = iw * ih;
            const float ua = fmaxf(area_a + bar[j] - inter, 1e-8f);
            if (inter * bu > bi * ua) { bi = inter; bu = ua; arg = j; }
        }

        const bool pos  = (2.0f * bi >= bu);          // iou_max >= 0.5
        const bool care = pos || (bi < 0.4f * bu);    // pos || iou_max < 0.4

        const float p0 = fminf(fmaxf(pc.x, 1e-4f), 0.9999f);
        const float p1 = fminf(fmaxf(pc.y, 1e-4f), 0.9999f);
        const float n0 = NEG_K * (p0 * p0) * (-__log2f(1.0f - p0));
        const float n1 = NEG_K * (p1 * p1) * (-__log2f(1.0f - p1));
        float term = n0 + n1;

        if (pos) {
            // rare path (~0.5% of anchors; a minority of waves hit it)
            np_acc += 1.0f;
            const int lab = slab[arg];
            const float pl = (lab == 0) ? p0 : p1;
            const float posterm =
                POS_K * ((1.0f - pl) * (1.0f - pl)) * (-__log2f(pl));
            term = posterm + ((lab == 0) ? n1 : n0);

            const float4 rg =
                *reinterpret_cast<const float4*>(regb + 4 * (size_t)a);
            const float acx = ab.x + 0.5f * aw;
            const float acy = ab.y + 0.5f * ah;
            const float t0r = __fdividef(sg[arg][0] - acx, aw) * 10.0f;
            const float t1r = __fdividef(sg[arg][1] - acy, ah) * 10.0f;
            const float t2r = (__log2f(sg[arg][2]) - __log2f(aw)) * (5.0f * LN2);
            const float t3r = (__log2f(sg[arg][3]) - __log2f(ah)) * (5.0f * LN2);
            const float rl = smooth_l1(t0r - rg.x) + smooth_l1(t1r - rg.y)
                           + smooth_l1(t2r - rg.z) + smooth_l1(t3r - rg.w);
            reg_acc += rl * sg[arg][4];
        }
        if (care) cls_acc += term;
    };

    const int a0 = blk * 256 + tid;   // [0, 32768)

    // 3 pairs of unconditional iterations: loads grouped, chains independent.
#pragma unroll
    for (int pp = 0; pp < 3; ++pp) {
        const int aA = a0 + (2 * pp) * S;
        const int aB = aA + S;
        const float4 abA = *reinterpret_cast<const float4*>(anc + 4 * (size_t)aA);
        const float4 abB = *reinterpret_cast<const float4*>(anc + 4 * (size_t)aB);
        const float2 pcA = *reinterpret_cast<const float2*>(clsb + 2 * (size_t)aA);
        const float2 pcB = *reinterpret_cast<const float2*>(clsb + 2 * (size_t)aB);
        body(abA, pcA, aA);
        body(abB, pcB, aB);
    }
    if (a0 < TAIL) {
        const int aT = a0 + 6 * S;
        const float4 abT = *reinterpret_cast<const float4*>(anc + 4 * (size_t)aT);
        const float2 pcT = *reinterpret_cast<const float2*>(clsb + 2 * (size_t)aT);
        body(abT, pcT, aT);
    }

    // block reduction: wave shuffle, then LDS across 4 waves
#pragma unroll
    for (int off = 32; off > 0; off >>= 1) {
        cls_acc += __shfl_down(cls_acc, off);
        reg_acc += __shfl_down(reg_acc, off);
        np_acc  += __shfl_down(np_acc,  off);
    }
    __shared__ float rbuf[4][3];
    const int wid = tid >> 6;
    if ((tid & 63) == 0) {
        rbuf[wid][0] = cls_acc;
        rbuf[wid][1] = reg_acc;
        rbuf[wid][2] = np_acc;
    }
    __syncthreads();
    if (tid == 0) {
        float c = 0.0f, r = 0.0f, n = 0.0f;
#pragma unroll
        for (int w = 0; w < 4; ++w) {
            c += rbuf[w][0]; r += rbuf[w][1]; n += rbuf[w][2];
        }
        // private slot per block -- no atomics, no pre-zeroing needed
        float* slot = ws + (size_t)(b * CHUNKS + blk) * 3;
        slot[0] = c; slot[1] = r; slot[2] = n;
    }
}

__global__ __launch_bounds__(256)
void focal_final(const float* __restrict__ ws, float* __restrict__ out)
{
    const int t = threadIdx.x;
    const int b = t >> 4;      // image
    const int c = t & 15;      // chunk-of-8 within image
    double sc = 0.0, sr = 0.0, sn = 0.0;
    const float* base = ws + (size_t)(b * CHUNKS + c * 8) * 3;
#pragma unroll
    for (int k = 0; k < 8; ++k) {
        sc += (double)base[k * 3 + 0];
        sr += (double)base[k * 3 + 1];
        sn += (double)base[k * 3 + 2];
    }
    // reduce across the 16 lanes of each image group (groups are 16-aligned)
#pragma unroll
    for (int off = 8; off > 0; off >>= 1) {
        sc += __shfl_down(sc, off);
        sr += __shfl_down(sr, off);
        sn += __shfl_down(sn, off);
    }
    __shared__ float lcl[B], lrl[B];
    if (c == 0) {
        const float C = (float)sc, R = (float)sr, N = (float)sn;
        lcl[b] = C / fmaxf(N, 1.0f);
        lrl[b] = (N > 0.0f) ? R / fmaxf(4.0f * N, 1.0f) : 0.0f;
    }
    __syncthreads();
    if (t == 0) {
        float a = 0.0f, d = 0.0f;
#pragma unroll
        for (int i = 0; i < B; ++i) { a += lcl[i]; d += lrl[i]; }
        out[0] = a * (1.0f / 16.0f);
        out[1] = d * (1.0f / 16.0f);
    }
}

} // namespace

extern "C" void kernel_launch(void* const* d_in, const int* in_sizes, int n_in,
                              void* d_out, int out_size, void* d_ws, size_t ws_size,
                              hipStream_t stream)
{
    const float* cls = (const float*)d_in[0];
    const float* reg = (const float*)d_in[1];
    const float* anc = (const float*)d_in[2];
    const float* ann = (const float*)d_in[3];
    float* out = (float*)d_out;
    float* ws  = (float*)d_ws;    // 16*128*3 f32 = 24 KB, fully overwritten

    dim3 grid(B, CHUNKS);         // x = image, y = anchor chunk (L2 sharing)
    focal_main<<<grid, dim3(256), 0, stream>>>(cls, reg, anc, ann, ws);
    focal_final<<<1, dim3(256), 0, stream>>>(ws, out);
}